// Round 2
// baseline (369.867 us; speedup 1.0000x reference)
//
#include <hip/hip_runtime.h>

#define NB 32
#define NP 512
#define NS 1024
#define NH 1024
#define NR 256
#define K3 3072

#define BM 64

typedef short short8 __attribute__((ext_vector_type(8)));
typedef __bf16 bf16x8 __attribute__((ext_vector_type(8)));
typedef float f32x4 __attribute__((ext_vector_type(4)));

__device__ __forceinline__ unsigned short f2bf(float f) {
  unsigned u = __builtin_bit_cast(unsigned, f);
  u += 0x7fffu + ((u >> 16) & 1u);   // round-to-nearest-even
  return (unsigned short)(u >> 16);
}

__device__ __forceinline__ f32x4 mfma_bf16(short8 a, short8 b, f32x4 c) {
  return __builtin_amdgcn_mfma_f32_16x16x32_bf16(
      __builtin_bit_cast(bf16x8, a), __builtin_bit_cast(bf16x8, b), c, 0, 0, 0);
}

// W fp32 [256][3072] -> FRAGMENT-MAJOR bf16 in ws:
//   WbF[kc][n16][lane] (short8), kc = k3/32 (96), n16 = n/16 (16), lane = lr+16*lg.
//   A wave's B-fragment load is one contiguous 1 KB burst (16 lines).
__global__ void wconv_kernel(const float* __restrict__ W,
                             unsigned short* __restrict__ WbF) {
  int i = blockIdx.x * blockDim.x + threadIdx.x;   // short8 id, 98304 total
  int lane = i & 63, n16 = (i >> 6) & 15, kc = i >> 10;
  int lr = lane & 15, lg = lane >> 4;
  const float* src = W + (size_t)(n16 * 16 + lr) * K3 + kc * 32 + lg * 8;
  float4 a = *(const float4*)src;
  float4 b = *(const float4*)(src + 4);
  short8 o;
  o[0] = (short)f2bf(a.x); o[1] = (short)f2bf(a.y);
  o[2] = (short)f2bf(a.z); o[3] = (short)f2bf(a.w);
  o[4] = (short)f2bf(b.x); o[5] = (short)f2bf(b.y);
  o[6] = (short)f2bf(b.z); o[7] = (short)f2bf(b.w);
  *(short8*)(WbF + (size_t)i * 8) = o;
}

// Fused gather + 3-part bf16 MFMA GEMM, SPLIT-K dual-group block.
// R2: R1's (1024,4) bound squeezed VGPRs to 64, which forced the scheduler to
// serialize the prefetch (waits moved to issue) -> 2x waves, 2x per-wave stall,
// net 0. And grid=256 means 1 block/CU regardless, so 2-blocks/CU was moot.
// Now: 1024 threads = 2 K-GROUPS x 8 waves. Group g owns K-cols [g*512,+512)
// in 8 barrier-stages (was 16), each group with its own double-buffered LDS
// tile and R0's proven register structure (VGPR~116 via launch_bounds(1024,2),
// 32-col waves with j=0,1 A-fragment reuse, 12-frag W ping-pong one stage
// ahead, depth-1 gather prefetch with full-compute slack). Final f32 reduce
// through LDS. Gather: 8 thr/pair, 8 CONTIGUOUS cols each -> ds_write_b128
// with all-8-chunk XOR coverage per instr (0 write bank conflicts, R1 lesson).
__global__ __launch_bounds__(1024, 2) void gemm_kernel(
    const int* __restrict__ pairs, const float* __restrict__ hs,
    const unsigned short* __restrict__ WbF, const float* __restrict__ bias,
    float* __restrict__ out) {
  __shared__ __align__(16) unsigned short sA[2][2][3][BM][64];  // 98304 B

  const int tid = threadIdx.x;
  const int blk = blockIdx.x;
  // XCD swizzle: blockIdx round-robins over 8 XCDs; give XCD x batches
  // 4x..4x+3 so a batch's 8 M-tiles share one XCD's L2 (R5: FETCH 122->63 MB).
  const int x     = blk & 7;
  const int jb    = blk >> 3;
  const int batch = x * 4 + (jb >> 3);
  const int mtile = jb & 7;
  const int m0    = (batch * 8 + mtile) * BM;

  const int g    = tid >> 9;          // K-group: 0 -> cols 0..511, 1 -> 512..1023
  const int gtid = tid & 511;

  // gather: 8 threads per pair; thread q covers float-cols q*8..q*8+7 (2x
  // contiguous float4) of each of the 4 source rows, within the group's half
  const int pairi = gtid >> 3;
  const int q     = gtid & 7;
  int4 pr = ((const int4*)pairs)[m0 + pairi];
  const float* hb = hs + (size_t)batch * NS * NH + (size_t)g * 512 + q * 8;
  const float* rp[4];
  rp[0] = hb + (size_t)pr.x * NH;   // h_start
  rp[1] = hb + (size_t)pr.y * NH;   // h_end
  rp[2] = hb + (size_t)pr.z * NH;   // t_start
  rp[3] = hb + (size_t)pr.w * NH;   // t_end

  // MFMA lane mapping: 8 waves per group, wave wg owns N-cols wg*32..wg*32+31
  const int lane = tid & 63;
  const int wg   = (tid >> 6) & 7;
  const int lr   = lane & 15;
  const int lg   = lane >> 4;

  // frag-major W: short addr = kc*8192 + n16*512 + lane*8; this wave n16=2wg+j;
  // this group's kc range per part: [g*16, g*16+16)
  const unsigned short* wbase =
      WbF + (size_t)(g * 16) * 8192 + (size_t)(wg * 2) * 512 + (size_t)lane * 8;

  f32x4 acc[4][2];
#pragma unroll
  for (int i = 0; i < 4; ++i)
#pragma unroll
    for (int j = 0; j < 2; ++j) acc[i][j] = (f32x4){0.f, 0.f, 0.f, 0.f};

  float4 ld[8];                 // gather prefetch: ld[2r+h]: row r, float4-half h
  short8 wcur[12], wnxt[12];    // W frags: idx = part*4 + ks*2 + j

  auto load_w = [&](int s, short8* wd) {
#pragma unroll
    for (int part = 0; part < 3; ++part)
#pragma unroll
      for (int ks = 0; ks < 2; ++ks)
#pragma unroll
        for (int j = 0; j < 2; ++j)
          wd[part * 4 + ks * 2 + j] = *(const short8*)(
              wbase + (size_t)(part * 32 + s * 2 + ks) * 8192 + (size_t)j * 512);
  };

  auto load_gather = [&](int s) {
    const int o = s * 64;
#pragma unroll
    for (int r = 0; r < 4; ++r) {
      ld[2 * r]     = *(const float4*)(rp[r] + o);
      ld[2 * r + 1] = *(const float4*)(rp[r] + o + 4);
    }
  };

  auto store_stage = [&](int buf) {
    short8 hv, tv, pv;
#pragma unroll
    for (int e = 0; e < 8; ++e) {
      const int hi = e >> 2, ei = e & 3;
      float h = 0.5f * (((const float*)&ld[0 + hi])[ei] + ((const float*)&ld[2 + hi])[ei]);
      float t = 0.5f * (((const float*)&ld[4 + hi])[ei] + ((const float*)&ld[6 + hi])[ei]);
      float p = h * t;                 // product in fp32, rounded once
      hv[e] = (short)f2bf(h); tv[e] = (short)f2bf(t); pv[e] = (short)f2bf(p);
    }
    const int col = (q ^ (pairi & 7)) * 8;   // XOR swizzle, all 8 chunks/instr
    *(short8*)&sA[g][buf][0][pairi][col] = hv;
    *(short8*)&sA[g][buf][1][pairi][col] = tv;
    *(short8*)&sA[g][buf][2][pairi][col] = pv;
  };

  auto compute = [&](int buf, short8* wc) {
#pragma unroll
    for (int ks = 0; ks < 2; ++ks) {
      short8 ah[4], at4[4], ap[4];
      const int col = (((ks * 4 + lg) ^ (lr & 7)) * 8);            // XOR swizzle
#pragma unroll
      for (int i = 0; i < 4; ++i) {
        ah[i]  = *(const short8*)&sA[g][buf][0][i * 16 + lr][col];
        at4[i] = *(const short8*)&sA[g][buf][1][i * 16 + lr][col];
        ap[i]  = *(const short8*)&sA[g][buf][2][i * 16 + lr][col];
      }
#pragma unroll
      for (int j = 0; j < 2; ++j)
#pragma unroll
        for (int i = 0; i < 4; ++i) {
          acc[i][j] = mfma_bf16(ah[i],  wc[0 + ks * 2 + j], acc[i][j]);
          acc[i][j] = mfma_bf16(at4[i], wc[4 + ks * 2 + j], acc[i][j]);
          acc[i][j] = mfma_bf16(ap[i],  wc[8 + ks * 2 + j], acc[i][j]);
        }
    }
  };

  // prologue: W(0) -> wcur, gather(0) -> LDS buf 0
  load_w(0, wcur);
  load_gather(0);
  store_stage(0);

  // stage s: sync on buf[s&1]+wc; issue W(s+1) FIRST in the vmem queue, then
  // gather(s+1); compute; store gather(s+1) into buf[s&1^1] (full-compute slack)
  auto stage = [&](int s, short8* wc, short8* wn) {
    __syncthreads();
    if (s < 7) {
      load_w(s + 1, wn);
      load_gather(s + 1);
    }
    compute(s & 1, wc);
    if (s < 7) store_stage((s & 1) ^ 1);
  };

#pragma unroll 1
  for (int sp = 0; sp < 4; ++sp) {       // 8 stages per group (was 16)
    stage(2 * sp,     wcur, wnxt);
    stage(2 * sp + 1, wnxt, wcur);
  }

  // Split-K reduction: group 1 spills acc to LDS (reuses sA), group 0 adds.
  float* ldsF = (float*)&sA[0][0][0][0][0];   // 64 KB used of 96 KB
  __syncthreads();                            // everyone done reading sA
  if (g == 1) {
#pragma unroll
    for (int i = 0; i < 4; ++i)
#pragma unroll
      for (int j = 0; j < 2; ++j) {
        const int k = i * 2 + j;
        *(f32x4*)&ldsF[(size_t)gtid * 32 + (size_t)((k ^ (gtid & 7)) * 4)] = acc[i][j];
      }
  }
  __syncthreads();
  if (g == 0) {
    // Epilogue: C/D layout row=(lane>>4)*4+reg, col=lane&15
#pragma unroll
    for (int i = 0; i < 4; ++i)
#pragma unroll
      for (int j = 0; j < 2; ++j) {
        const int k = i * 2 + j;
        f32x4 o1 = *(const f32x4*)&ldsF[(size_t)gtid * 32 + (size_t)((k ^ (gtid & 7)) * 4)];
        const int col  = wg * 32 + j * 16 + lr;
        const float bv = bias[col];
        const size_t rbase = (size_t)(m0 + i * 16 + lg * 4) * NR + col;
#pragma unroll
        for (int r = 0; r < 4; ++r)
          out[rbase + (size_t)r * NR] = acc[i][j][r] + o1[r] + bv;
      }
  }
}

extern "C" void kernel_launch(void* const* d_in, const int* in_sizes, int n_in,
                              void* d_out, int out_size, void* d_ws, size_t ws_size,
                              hipStream_t stream) {
  const int*   pairs = (const int*)d_in[0];
  const float* hs    = (const float*)d_in[1];
  const float* W     = (const float*)d_in[2];
  const float* bias  = (const float*)d_in[3];
  float* out = (float*)d_out;
  unsigned short* WbF = (unsigned short*)d_ws;   // 1.5 MB frag-major bf16 W

  wconv_kernel<<<(96 * 16 * 64) / 256, 256, 0, stream>>>(W, WbF);
  gemm_kernel<<<(NB * NP) / BM, 1024, 0, stream>>>(pairs, hs, WbF, bias, out);
}

// Round 3
// 241.028 us; speedup vs baseline: 1.5345x; 1.5345x over previous
//
#include <hip/hip_runtime.h>

#define NB 32
#define NP 512
#define NS 1024
#define NH 1024
#define NR 256
#define K3 3072

#define BM 32

typedef short short8 __attribute__((ext_vector_type(8)));
typedef short short4v __attribute__((ext_vector_type(4)));
typedef __bf16 bf16x8 __attribute__((ext_vector_type(8)));
typedef float f32x4 __attribute__((ext_vector_type(4)));

__device__ __forceinline__ unsigned short f2bf(float f) {
  unsigned u = __builtin_bit_cast(unsigned, f);
  u += 0x7fffu + ((u >> 16) & 1u);   // round-to-nearest-even
  return (unsigned short)(u >> 16);
}

__device__ __forceinline__ f32x4 mfma_bf16(short8 a, short8 b, f32x4 c) {
  return __builtin_amdgcn_mfma_f32_16x16x32_bf16(
      __builtin_bit_cast(bf16x8, a), __builtin_bit_cast(bf16x8, b), c, 0, 0, 0);
}

// W fp32 [256][3072] -> FRAGMENT-MAJOR bf16 in ws:
//   WbF[kc][n16][lane] (short8), kc = k3/32 (96), n16 = n/16 (16), lane = lr+16*lg.
//   A wave's B-fragment load is one contiguous 1 KB burst (16 lines).
__global__ void wconv_kernel(const float* __restrict__ W,
                             unsigned short* __restrict__ WbF) {
  int i = blockIdx.x * blockDim.x + threadIdx.x;   // short8 id, 98304 total
  int lane = i & 63, n16 = (i >> 6) & 15, kc = i >> 10;
  int lr = lane & 15, lg = lane >> 4;
  const float* src = W + (size_t)(n16 * 16 + lr) * K3 + kc * 32 + lg * 8;
  float4 a = *(const float4*)src;
  float4 b = *(const float4*)(src + 4);
  short8 o;
  o[0] = (short)f2bf(a.x); o[1] = (short)f2bf(a.y);
  o[2] = (short)f2bf(a.z); o[3] = (short)f2bf(a.w);
  o[4] = (short)f2bf(b.x); o[5] = (short)f2bf(b.y);
  o[6] = (short)f2bf(b.z); o[7] = (short)f2bf(b.w);
  *(short8*)(WbF + (size_t)i * 8) = o;
}

// Fused gather + 3-part bf16 MFMA GEMM.
// R3: R0's proven single-block structure (VGPR=116, no spill, depth-1 gather
// prefetch with full-compute vmcnt slack, 12-frag W ping-pong one stage
// ahead), but BM 64->32 and grid 256->512 so each CU gets TWO independent
// workgroups. Independent barriers => when one block parks at __syncthreads
// behind a slow gather, the other block's 8 waves keep the MFMA pipe busy.
// (R1/R2 lesson: hipcc treats launch_bounds arg2 as min BLOCKS/CU; 1024-thread
// blocks get capped at 64 VGPR -> serialization/spill. And an intra-block
// split-K shares one barrier, so it never overlaps. Stay at 512 threads.)
// W stream doubles (768 MB, L2-resident per XCD) -- acceptable; gather traffic
// unchanged (pairs are split across blocks, not duplicated).
__global__ __launch_bounds__(512, 2) void gemm_kernel(
    const int* __restrict__ pairs, const float* __restrict__ hs,
    const unsigned short* __restrict__ WbF, const float* __restrict__ bias,
    float* __restrict__ out) {
  __shared__ __align__(16) unsigned short sA[2][3][BM][64];  // 24576 B

  const int tid = threadIdx.x;
  const int blk = blockIdx.x;
  // XCD swizzle: blockIdx round-robins over 8 XCDs; give XCD x batches
  // 4x..4x+3 (each batch = 16 M-tiles now) so a batch's hs (4 MB) and W
  // (1.5 MB) stay in one XCD's L2.
  const int x     = blk & 7;
  const int jb    = blk >> 3;          // 0..63
  const int batch = x * 4 + (jb >> 4);
  const int mtile = jb & 15;
  const int m0    = (batch * 16 + mtile) * BM;

  // gather: 16 threads per pair; thread q covers float-cols {4q..4q+3} of each
  // of the 4 source rows (one float4 per row per stage) -- R1's 0-conflict shape
  const int pairi = tid >> 4;          // 0..31
  const int q     = tid & 15;
  int4 pr = ((const int4*)pairs)[m0 + pairi];
  const float* hb = hs + (size_t)batch * NS * NH + 4 * q;
  const float* rp[4];
  rp[0] = hb + (size_t)pr.x * NH;   // h_start
  rp[1] = hb + (size_t)pr.y * NH;   // h_end
  rp[2] = hb + (size_t)pr.z * NH;   // t_start
  rp[3] = hb + (size_t)pr.w * NH;   // t_end

  // MFMA lane mapping: 8 waves, wave w owns N-cols w*32..w*32+31
  const int lane = tid & 63;
  const int w    = tid >> 6;
  const int lr   = lane & 15;
  const int lg   = lane >> 4;

  // frag-major W: short addr = kc*8192 + n16*512 + lane*8; this wave: n16=2w+j
  const unsigned short* wbase = WbF + (size_t)(w * 2) * 512 + (size_t)lane * 8;

  f32x4 acc[2][2];
#pragma unroll
  for (int i = 0; i < 2; ++i)
#pragma unroll
    for (int j = 0; j < 2; ++j) acc[i][j] = (f32x4){0.f, 0.f, 0.f, 0.f};

  float4 ld[4];                 // gather prefetch: ld[r] = row r's float4
  short8 wcur[12], wnxt[12];    // W frags: idx = part*4 + ks*2 + j

  auto load_w = [&](int s, short8* wd) {
#pragma unroll
    for (int part = 0; part < 3; ++part)
#pragma unroll
      for (int ks = 0; ks < 2; ++ks)
#pragma unroll
        for (int j = 0; j < 2; ++j)
          wd[part * 4 + ks * 2 + j] = *(const short8*)(
              wbase + (size_t)(part * 32 + s * 2 + ks) * 8192 + (size_t)j * 512);
  };

  auto load_gather = [&](int s) {
    const int o = s * 64;
#pragma unroll
    for (int r = 0; r < 4; ++r)
      ld[r] = *(const float4*)(rp[r] + o);
  };

  auto store_stage = [&](int buf) {
    short4v hv, tv, pv;
#pragma unroll
    for (int e = 0; e < 4; ++e) {
      float h = 0.5f * (((const float*)&ld[0])[e] + ((const float*)&ld[1])[e]);
      float t = 0.5f * (((const float*)&ld[2])[e] + ((const float*)&ld[3])[e]);
      float p = h * t;                 // product in fp32, rounded once
      hv[e] = (short)f2bf(h); tv[e] = (short)f2bf(t); pv[e] = (short)f2bf(p);
    }
    const int chunkI = q >> 1;
    const int col = ((chunkI ^ (pairi & 7)) * 8) + (q & 1) * 4;  // XOR swizzle
    *(short4v*)&sA[buf][0][pairi][col] = hv;
    *(short4v*)&sA[buf][1][pairi][col] = tv;
    *(short4v*)&sA[buf][2][pairi][col] = pv;
  };

  auto compute = [&](int buf, short8* wc) {
#pragma unroll
    for (int ks = 0; ks < 2; ++ks) {
      short8 ah[2], at4[2], ap[2];
      const int col = (((ks * 4 + lg) ^ (lr & 7)) * 8);            // XOR swizzle
#pragma unroll
      for (int i = 0; i < 2; ++i) {
        ah[i]  = *(const short8*)&sA[buf][0][i * 16 + lr][col];
        at4[i] = *(const short8*)&sA[buf][1][i * 16 + lr][col];
        ap[i]  = *(const short8*)&sA[buf][2][i * 16 + lr][col];
      }
#pragma unroll
      for (int j = 0; j < 2; ++j)
#pragma unroll
        for (int i = 0; i < 2; ++i) {
          acc[i][j] = mfma_bf16(ah[i],  wc[0 + ks * 2 + j], acc[i][j]);
          acc[i][j] = mfma_bf16(at4[i], wc[4 + ks * 2 + j], acc[i][j]);
          acc[i][j] = mfma_bf16(ap[i],  wc[8 + ks * 2 + j], acc[i][j]);
        }
    }
  };

  // prologue: W(0) -> wcur, gather(0) -> LDS buf 0
  load_w(0, wcur);
  load_gather(0);
  store_stage(0);

  // stage s: sync on buf[s&1]+wc; issue W(s+1) FIRST in the vmem queue, then
  // gather(s+1); compute (registers+LDS only); store with full-compute slack.
  auto stage = [&](int s, short8* wc, short8* wn) {
    __syncthreads();
    if (s < 15) {
      load_w(s + 1, wn);
      load_gather(s + 1);
    }
    compute(s & 1, wc);
    if (s < 15) store_stage((s & 1) ^ 1);
  };

#pragma unroll 1
  for (int sp = 0; sp < 8; ++sp) {       // ping-pong W register buffers
    stage(2 * sp,     wcur, wnxt);
    stage(2 * sp + 1, wnxt, wcur);
  }

  // Epilogue: C/D layout row=(lane>>4)*4+reg, col=lane&15
#pragma unroll
  for (int j = 0; j < 2; ++j) {
    const int col  = w * 32 + j * 16 + lr;
    const float bv = bias[col];
#pragma unroll
    for (int i = 0; i < 2; ++i) {
      const size_t rbase = (size_t)(m0 + i * 16 + lg * 4) * NR + col;
#pragma unroll
      for (int r = 0; r < 4; ++r)
        out[rbase + (size_t)r * NR] = acc[i][j][r] + bv;
    }
  }
}

extern "C" void kernel_launch(void* const* d_in, const int* in_sizes, int n_in,
                              void* d_out, int out_size, void* d_ws, size_t ws_size,
                              hipStream_t stream) {
  const int*   pairs = (const int*)d_in[0];
  const float* hs    = (const float*)d_in[1];
  const float* W     = (const float*)d_in[2];
  const float* bias  = (const float*)d_in[3];
  float* out = (float*)d_out;
  unsigned short* WbF = (unsigned short*)d_ws;   // 1.5 MB frag-major bf16 W

  wconv_kernel<<<(96 * 16 * 64) / 256, 256, 0, stream>>>(W, WbF);
  gemm_kernel<<<(NB * NP) / BM, 512, 0, stream>>>(pairs, hs, WbF, bias, out);
}